// Round 8
// baseline (201.806 us; speedup 1.0000x reference)
//
#include <hip/hip_runtime.h>
#include <cstdint>

// ============================================================================
// ROUND 8: MEASUREMENT ROUND. The R6 kernel (barrier-free wave-private,
// 178.2 us total) launched TWICE per kernel_launch. Idempotent: identical
// inputs -> identical outputs both times; same work on every call.
// total = fixed_overhead + 2*K  =>  K = total - 178.2
// ============================================================================

#define BLK 256
#define WAVES 4
#define SPW 4                      // samples per wave
#define SPB (WAVES*SPW)            // 16 samples per block
#define WPS 196                    // packed sign words (and float4s) per sample
#define HDRW 16                    // 64 B zero header (absorbs top/left OOB)
#define SLAB (SPW*WPS)             // 784 words per wave slab
#define XS_INTS (HDRW + WAVES*SLAB)
#define YS_W 33                    // ysi words per sample (132 B, 125 used)
#define YSLAB (SPW*YS_W)           // 132 words per wave

#define W0_OFF  0
#define W1P_OFF 30
#define FC_OFF  45
#define CSC_OFF 375
#define CBI_OFF 380
#define FSC_OFF 385
#define FBI_OFF 395
#define WS_TOT  405

#if defined(__has_builtin)
# if __has_builtin(__builtin_amdgcn_sdot4)
#  define HAVE_SDOT4 1
# endif
#endif

__device__ __forceinline__ int dot4i8(int a, int b, int c) {
#ifdef HAVE_SDOT4
    return __builtin_amdgcn_sdot4(a, b, c, false);
#else
    int r = c;
    r += (((int)(a << 24)) >> 24) * (((int)(b << 24)) >> 24);
    r += (((int)(a << 16)) >> 24) * (((int)(b << 16)) >> 24);
    r += (((int)(a <<  8)) >> 24) * (((int)(b <<  8)) >> 24);
    r += (a >> 24) * (b >> 24);
    return r;
#endif
}

__device__ __forceinline__ int pack_sign4(float4 v) {
    int b0 = (v.x > 0.f) - (v.x < 0.f);
    int b1 = (v.y > 0.f) - (v.y < 0.f);
    int b2 = (v.z > 0.f) - (v.z < 0.f);
    int b3 = (v.w > 0.f) - (v.w < 0.f);
    return (b0 & 0xFF) | ((b1 & 0xFF) << 8) | ((b2 & 0xFF) << 16) | (b3 << 24);
}

__device__ __forceinline__ int sign8(float f) { return (f > 0.f) - (f < 0.f); }

__global__ __launch_bounds__(BLK, 4)
void bnn_fused(const float* __restrict__ x,
               const float* __restrict__ conv_w, const float* __restrict__ conv_b,
               const float* __restrict__ bn2_g,  const float* __restrict__ bn2_b,
               const float* __restrict__ bn2_m,  const float* __restrict__ bn2_v,
               const float* __restrict__ fc_w,   const float* __restrict__ fc_b,
               const float* __restrict__ bn1_g,  const float* __restrict__ bn1_b,
               const float* __restrict__ bn1_m,  const float* __restrict__ bn1_v,
               float* __restrict__ out)
{
    __shared__ int xsi[XS_INTS];
    __shared__ int ysi[WAVES * YSLAB];
    __shared__ int wsS[WS_TOT];

    const int tid  = threadIdx.x;
    const int lane = tid & 63;
    const int wid  = tid >> 6;
    const int blk  = blockIdx.x;

    const float4* xg = (const float4*)x + ((size_t)blk * SPB + wid * SPW) * WPS;
    float4 v[12]; float4 vr;
    #pragma unroll
    for (int k = 0; k < 12; k++) v[k] = xg[lane + k * 64];
    const bool hasr = lane < (SLAB - 12 * 64);
    if (hasr) vr = xg[lane + 12 * 64];

    if (tid < 30) {
        int c = tid / 6, kr = tid - c * 6;
        const float* wp = conv_w + c * 36 + kr * 6;
        uint32_t a = 0;
        #pragma unroll
        for (int k = 0; k < 4; k++) a |= (uint32_t)(sign8(wp[k]) & 0xFF) << (8 * k);
        wsS[W0_OFF + tid] = (int)a;
    } else if (tid >= 32 && tid < 47) {
        int i = tid - 32, c = i / 3, p = i - c * 3;
        const float* wp = conv_w + c * 36;
        uint32_t a = 0;
        a |= (uint32_t)(sign8(wp[(2*p)*6 + 4]) & 0xFF);
        a |= (uint32_t)(sign8(wp[(2*p)*6 + 5]) & 0xFF) << 8;
        a |= (uint32_t)(sign8(wp[(2*p+1)*6 + 4]) & 0xFF) << 16;
        a |= (uint32_t)(sign8(wp[(2*p+1)*6 + 5]) & 0xFF) << 24;
        wsS[W1P_OFF + i] = (int)a;
    } else if (tid >= 48 && tid < 53) {
        int c = tid - 48;
        float sc = bn2_g[c] / sqrtf(bn2_v[c] + 1e-5f);
        wsS[CSC_OFF + c] = __float_as_int(sc);
        wsS[CBI_OFF + c] = __float_as_int((conv_b[c] - bn2_m[c]) * sc + bn2_b[c]);
    } else if (tid >= 64 && tid < 74) {
        int o = tid - 64;
        float sc = bn1_g[o] / sqrtf(bn1_v[o] + 1e-5f);
        wsS[FSC_OFF + o] = __float_as_int(sc);
        wsS[FBI_OFF + o] = __float_as_int((fc_b[o] - bn1_m[o]) * sc + bn1_b[o]);
    }
    for (int i = tid; i < 330; i += BLK) {
        int o = i / 33, w = i - o * 33;
        uint32_t m = 0;
        #pragma unroll
        for (int k = 0; k < 4; k++) {
            int kk = w * 4 + k;
            if (kk < 125) m |= (uint32_t)(sign8(fc_w[o * 125 + kk]) & 0xFF) << (8 * k);
        }
        wsS[FC_OFF + i] = (int)m;
    }
    if (tid < HDRW) xsi[tid] = 0;

    __syncthreads();

    ysi[wid * YSLAB + lane]      = 0;
    ysi[wid * YSLAB + lane + 64] = 0;
    if (lane < YSLAB - 128) ysi[wid * YSLAB + 128 + lane] = 0;

    int* xsw = xsi + HDRW + wid * SLAB;
    #pragma unroll
    for (int k = 0; k < 12; k++) xsw[lane + k * 64] = pack_sign4(v[k]);
    if (hasr) xsw[lane + 12 * 64] = pack_sign4(vr);

    {
        int w0[30], w1p[15]; float csc[5], cbi[5];
        #pragma unroll
        for (int i = 0; i < 30; i++) w0[i]  = wsS[W0_OFF + i];
        #pragma unroll
        for (int i = 0; i < 15; i++) w1p[i] = wsS[W1P_OFF + i];
        #pragma unroll
        for (int c = 0; c < 5; c++) {
            csc[c] = __int_as_float(wsS[CSC_OFF + c]);
            cbi[c] = __int_as_float(wsS[CBI_OFF + c]);
        }
        #pragma unroll
        for (int it = 0; it < 2; it++) {
            int jw = lane + it * 64;
            if (jw < SPW * 25) {
                int sl = jw / 25, pos = jw - sl * 25;
                int ss = wid * SPW + sl;
                int oh = pos / 5, ow  = pos - oh * 5;
                int rowb = ss * 784 + 168 * oh + 6 * ow - 58;
                int q  = (64 + rowb) >> 2;
                int sh = (rowb & 3) * 8;
                uint32_t emask = (ow == 0) ? 0xFFFF0000u : 0xFFFFFFFFu;
                uint32_t e0[6], e1[6];
                #pragma unroll
                for (int kr = 0; kr < 6; kr++) {
                    int a = q + 7 * kr;
                    if (kr < 2) a = (oh == 0) ? 0 : a;
                    uint32_t a0 = (uint32_t)xsi[a];
                    uint32_t a1 = (uint32_t)xsi[a + 1];
                    uint64_t vv = ((((uint64_t)a1) << 32) | a0) >> sh;
                    e0[kr] = (uint32_t)vv & emask;
                    e1[kr] = (uint32_t)(vv >> 32) & 0xFFFFu;
                }
                uint32_t e1p[3];
                #pragma unroll
                for (int p = 0; p < 3; p++) e1p[p] = e1[2*p] | (e1[2*p+1] << 16);
                #pragma unroll
                for (int c = 0; c < 5; c++) {
                    int acc = 0;
                    #pragma unroll
                    for (int kr = 0; kr < 6; kr++) acc = dot4i8((int)e0[kr], w0[c*6+kr], acc);
                    #pragma unroll
                    for (int p = 0; p < 3; p++)    acc = dot4i8((int)e1p[p], w1p[c*3+p], acc);
                    float yv = (float)acc * csc[c] + cbi[c];
                    ((signed char*)ysi)[(ss * YS_W) * 4 + c * 25 + pos] = (signed char)sign8(yv);
                }
            }
        }
    }

    {
        int sl = lane >> 4;
        int oo = lane & 15;
        int ss = wid * SPW + sl;
        int oc = (oo < 10) ? oo : 0;
        int acc = 0;
        #pragma unroll
        for (int w = 0; w < 32; w++)
            acc = dot4i8(ysi[ss * YS_W + w], wsS[FC_OFF + oc * 33 + w], acc);
        float z = (oo < 10)
            ? (float)acc * __int_as_float(wsS[FSC_OFF + oc]) + __int_as_float(wsS[FBI_OFF + oc])
            : -1e30f;
        float mx = z;
        #pragma unroll
        for (int m = 1; m < 16; m <<= 1) mx = fmaxf(mx, __shfl_xor(mx, m, 16));
        float e = (oo < 10) ? __expf(z - mx) : 0.f;
        float sum = e;
        #pragma unroll
        for (int m = 1; m < 16; m <<= 1) sum += __shfl_xor(sum, m, 16);
        float res = z - mx - __logf(sum);
        if (oo < 10)
            out[((size_t)blk * SPB + ss) * 10 + oo] = res;
    }
}

extern "C" void kernel_launch(void* const* d_in, const int* in_sizes, int n_in,
                              void* d_out, int out_size, void* d_ws, size_t ws_size,
                              hipStream_t stream)
{
    const float* xp     = (const float*)d_in[0];
    const float* conv_w = (const float*)d_in[1];
    const float* conv_b = (const float*)d_in[2];
    const float* bn2_g  = (const float*)d_in[3];
    const float* bn2_b  = (const float*)d_in[4];
    const float* bn2_m  = (const float*)d_in[5];
    const float* bn2_v  = (const float*)d_in[6];
    const float* fc_w   = (const float*)d_in[7];
    const float* fc_b   = (const float*)d_in[8];
    const float* bn1_g  = (const float*)d_in[9];
    const float* bn1_b  = (const float*)d_in[10];
    const float* bn1_m  = (const float*)d_in[11];
    const float* bn1_v  = (const float*)d_in[12];
    float* outp = (float*)d_out;

    const int B = in_sizes[0] / 784;      // 32768
    const int grid = B / SPB;             // 2048

    // MEASUREMENT: same kernel twice (idempotent). K = total - 178.2us.
    bnn_fused<<<grid, BLK, 0, stream>>>(xp, conv_w, conv_b,
                                        bn2_g, bn2_b, bn2_m, bn2_v,
                                        fc_w, fc_b, bn1_g, bn1_b, bn1_m, bn1_v,
                                        outp);
    bnn_fused<<<grid, BLK, 0, stream>>>(xp, conv_w, conv_b,
                                        bn2_g, bn2_b, bn2_m, bn2_v,
                                        fc_w, fc_b, bn1_g, bn1_b, bn1_m, bn1_v,
                                        outp);
}

// Round 9
// 177.421 us; speedup vs baseline: 1.1374x; 1.1374x over previous
//
#include <hip/hip_runtime.h>
#include <cstdint>

// ============================================================================
// FINAL: R6 barrier-free wave-private kernel, single launch (best: 178.2 us).
// R8 measurement: marginal kernel cost = 23.6 us (incl. launch gap) vs a
// 19-21 us floor for the mandatory 103 MB x-read at the ~6.5-6.9 TB/s
// harness-demonstrated stream rate + launch tail => within a few percent of
// the memory roofline. Remaining bench time (~155 us) is harness-fixed
// restore/poison fills running at 86% of HBM peak.
// ============================================================================

#define BLK 256
#define WAVES 4
#define SPW 4                      // samples per wave
#define SPB (WAVES*SPW)            // 16 samples per block
#define WPS 196                    // packed sign words (and float4s) per sample
#define HDRW 16                    // 64 B zero header (absorbs top/left OOB)
#define SLAB (SPW*WPS)             // 784 words per wave slab
#define XS_INTS (HDRW + WAVES*SLAB)
#define YS_W 33                    // ysi words per sample (132 B, 125 used)
#define YSLAB (SPW*YS_W)           // 132 words per wave

#define W0_OFF  0                  // 30: conv w bytes kc0..3 per (c*6+kr)
#define W1P_OFF 30                 // 15: conv w {kc4,kc5} rows 2p,2p+1 per (c*3+p)
#define FC_OFF  45                 // 330: fc i8 sign words, o*33+w
#define CSC_OFF 375                // 5: conv folded scale
#define CBI_OFF 380                // 5: conv folded bias
#define FSC_OFF 385                // 10: fc folded scale
#define FBI_OFF 395                // 10: fc folded bias
#define WS_TOT  405

#if defined(__has_builtin)
# if __has_builtin(__builtin_amdgcn_sdot4)
#  define HAVE_SDOT4 1
# endif
#endif

__device__ __forceinline__ int dot4i8(int a, int b, int c) {
#ifdef HAVE_SDOT4
    return __builtin_amdgcn_sdot4(a, b, c, false);
#else
    int r = c;
    r += (((int)(a << 24)) >> 24) * (((int)(b << 24)) >> 24);
    r += (((int)(a << 16)) >> 24) * (((int)(b << 16)) >> 24);
    r += (((int)(a <<  8)) >> 24) * (((int)(b <<  8)) >> 24);
    r += (a >> 24) * (b >> 24);
    return r;
#endif
}

__device__ __forceinline__ int pack_sign4(float4 v) {
    int b0 = (v.x > 0.f) - (v.x < 0.f);
    int b1 = (v.y > 0.f) - (v.y < 0.f);
    int b2 = (v.z > 0.f) - (v.z < 0.f);
    int b3 = (v.w > 0.f) - (v.w < 0.f);
    return (b0 & 0xFF) | ((b1 & 0xFF) << 8) | ((b2 & 0xFF) << 16) | (b3 << 24);
}

__device__ __forceinline__ int sign8(float f) { return (f > 0.f) - (f < 0.f); }

__global__ __launch_bounds__(BLK, 4)
void bnn_fused(const float* __restrict__ x,
               const float* __restrict__ conv_w, const float* __restrict__ conv_b,
               const float* __restrict__ bn2_g,  const float* __restrict__ bn2_b,
               const float* __restrict__ bn2_m,  const float* __restrict__ bn2_v,
               const float* __restrict__ fc_w,   const float* __restrict__ fc_b,
               const float* __restrict__ bn1_g,  const float* __restrict__ bn1_b,
               const float* __restrict__ bn1_m,  const float* __restrict__ bn1_v,
               float* __restrict__ out)
{
    __shared__ int xsi[XS_INTS];        // header + 4 wave-private sign slabs
    __shared__ int ysi[WAVES * YSLAB];  // wave-private conv-output sign bytes
    __shared__ int wsS[WS_TOT];         // block-shared packed weights/affines

    const int tid  = threadIdx.x;
    const int lane = tid & 63;
    const int wid  = tid >> 6;
    const int blk  = blockIdx.x;

    // ---- issue this wave's x loads first (12 float4/lane + 16-lane tail) ----
    const float4* xg = (const float4*)x + ((size_t)blk * SPB + wid * SPW) * WPS;
    float4 v[12]; float4 vr;
    #pragma unroll
    for (int k = 0; k < 12; k++) v[k] = xg[lane + k * 64];
    const bool hasr = lane < (SLAB - 12 * 64);          // 16
    if (hasr) vr = xg[lane + 12 * 64];

    // ---- block-coop weight build (tiny, L2-resident) ----
    if (tid < 30) {
        int c = tid / 6, kr = tid - c * 6;
        const float* wp = conv_w + c * 36 + kr * 6;
        uint32_t a = 0;
        #pragma unroll
        for (int k = 0; k < 4; k++) a |= (uint32_t)(sign8(wp[k]) & 0xFF) << (8 * k);
        wsS[W0_OFF + tid] = (int)a;
    } else if (tid >= 32 && tid < 47) {
        int i = tid - 32, c = i / 3, p = i - c * 3;
        const float* wp = conv_w + c * 36;
        uint32_t a = 0;
        a |= (uint32_t)(sign8(wp[(2*p)*6 + 4]) & 0xFF);
        a |= (uint32_t)(sign8(wp[(2*p)*6 + 5]) & 0xFF) << 8;
        a |= (uint32_t)(sign8(wp[(2*p+1)*6 + 4]) & 0xFF) << 16;
        a |= (uint32_t)(sign8(wp[(2*p+1)*6 + 5]) & 0xFF) << 24;
        wsS[W1P_OFF + i] = (int)a;
    } else if (tid >= 48 && tid < 53) {
        int c = tid - 48;
        float sc = bn2_g[c] / sqrtf(bn2_v[c] + 1e-5f);
        wsS[CSC_OFF + c] = __float_as_int(sc);
        wsS[CBI_OFF + c] = __float_as_int((conv_b[c] - bn2_m[c]) * sc + bn2_b[c]);
    } else if (tid >= 64 && tid < 74) {
        int o = tid - 64;
        float sc = bn1_g[o] / sqrtf(bn1_v[o] + 1e-5f);
        wsS[FSC_OFF + o] = __float_as_int(sc);
        wsS[FBI_OFF + o] = __float_as_int((fc_b[o] - bn1_m[o]) * sc + bn1_b[o]);
    }
    for (int i = tid; i < 330; i += BLK) {
        int o = i / 33, w = i - o * 33;
        uint32_t m = 0;
        #pragma unroll
        for (int k = 0; k < 4; k++) {
            int kk = w * 4 + k;
            if (kk < 125) m |= (uint32_t)(sign8(fc_w[o * 125 + kk]) & 0xFF) << (8 * k);
        }
        wsS[FC_OFF + i] = (int)m;
    }
    if (tid < HDRW) xsi[tid] = 0;       // zero header (published by the barrier)

    __syncthreads();   // the ONLY barrier: publishes wsS + header

    // ---- wave-private from here on ----
    ysi[wid * YSLAB + lane]      = 0;
    ysi[wid * YSLAB + lane + 64] = 0;
    if (lane < YSLAB - 128) ysi[wid * YSLAB + 128 + lane] = 0;

    int* xsw = xsi + HDRW + wid * SLAB;
    #pragma unroll
    for (int k = 0; k < 12; k++) xsw[lane + k * 64] = pack_sign4(v[k]);
    if (hasr) xsw[lane + 12 * 64] = pack_sign4(vr);

    // ---- conv: lane owns (sample,pos) for all 5 channels ----
    {
        int w0[30], w1p[15]; float csc[5], cbi[5];
        #pragma unroll
        for (int i = 0; i < 30; i++) w0[i]  = wsS[W0_OFF + i];
        #pragma unroll
        for (int i = 0; i < 15; i++) w1p[i] = wsS[W1P_OFF + i];
        #pragma unroll
        for (int c = 0; c < 5; c++) {
            csc[c] = __int_as_float(wsS[CSC_OFF + c]);
            cbi[c] = __int_as_float(wsS[CBI_OFF + c]);
        }
        #pragma unroll
        for (int it = 0; it < 2; it++) {
            int jw = lane + it * 64;                    // wave items 0..99
            if (jw < SPW * 25) {
                int sl = jw / 25, pos = jw - sl * 25;
                int ss = wid * SPW + sl;
                int oh = pos / 5, ow  = pos - oh * 5;
                int rowb = ss * 784 + 168 * oh + 6 * ow - 58;
                int q  = (64 + rowb) >> 2;
                int sh = (rowb & 3) * 8;
                uint32_t emask = (ow == 0) ? 0xFFFF0000u : 0xFFFFFFFFu;
                uint32_t e0[6], e1[6];
                #pragma unroll
                for (int kr = 0; kr < 6; kr++) {
                    int a = q + 7 * kr;
                    if (kr < 2) a = (oh == 0) ? 0 : a;  // ih<0 rows -> zero header
                    uint32_t a0 = (uint32_t)xsi[a];
                    uint32_t a1 = (uint32_t)xsi[a + 1];
                    uint64_t vv = ((((uint64_t)a1) << 32) | a0) >> sh;
                    e0[kr] = (uint32_t)vv & emask;      // left-edge pad -> 0
                    e1[kr] = (uint32_t)(vv >> 32) & 0xFFFFu;
                }
                uint32_t e1p[3];
                #pragma unroll
                for (int p = 0; p < 3; p++) e1p[p] = e1[2*p] | (e1[2*p+1] << 16);
                #pragma unroll
                for (int c = 0; c < 5; c++) {
                    int acc = 0;
                    #pragma unroll
                    for (int kr = 0; kr < 6; kr++) acc = dot4i8((int)e0[kr], w0[c*6+kr], acc);
                    #pragma unroll
                    for (int p = 0; p < 3; p++)    acc = dot4i8((int)e1p[p], w1p[c*3+p], acc);
                    float yv = (float)acc * csc[c] + cbi[c];  // hardtanh preserves sign
                    ((signed char*)ysi)[(ss * YS_W) * 4 + c * 25 + pos] = (signed char)sign8(yv);
                }
            }
        }
    }

    // ---- FC + log_softmax, in-wave (16-lane shuffle butterflies) ----
    {
        int sl = lane >> 4;                 // 4 samples per wave
        int oo = lane & 15;
        int ss = wid * SPW + sl;
        int oc = (oo < 10) ? oo : 0;
        int acc = 0;
        #pragma unroll
        for (int w = 0; w < 32; w++)
            acc = dot4i8(ysi[ss * YS_W + w], wsS[FC_OFF + oc * 33 + w], acc);
        float z = (oo < 10)
            ? (float)acc * __int_as_float(wsS[FSC_OFF + oc]) + __int_as_float(wsS[FBI_OFF + oc])
            : -1e30f;
        float mx = z;
        #pragma unroll
        for (int m = 1; m < 16; m <<= 1) mx = fmaxf(mx, __shfl_xor(mx, m, 16));
        float e = (oo < 10) ? __expf(z - mx) : 0.f;
        float sum = e;
        #pragma unroll
        for (int m = 1; m < 16; m <<= 1) sum += __shfl_xor(sum, m, 16);
        float res = z - mx - __logf(sum);
        if (oo < 10)
            out[((size_t)blk * SPB + ss) * 10 + oo] = res;
    }
}

extern "C" void kernel_launch(void* const* d_in, const int* in_sizes, int n_in,
                              void* d_out, int out_size, void* d_ws, size_t ws_size,
                              hipStream_t stream)
{
    const float* xp     = (const float*)d_in[0];
    const float* conv_w = (const float*)d_in[1];
    const float* conv_b = (const float*)d_in[2];
    const float* bn2_g  = (const float*)d_in[3];
    const float* bn2_b  = (const float*)d_in[4];
    const float* bn2_m  = (const float*)d_in[5];
    const float* bn2_v  = (const float*)d_in[6];
    const float* fc_w   = (const float*)d_in[7];
    const float* fc_b   = (const float*)d_in[8];
    const float* bn1_g  = (const float*)d_in[9];
    const float* bn1_b  = (const float*)d_in[10];
    const float* bn1_m  = (const float*)d_in[11];
    const float* bn1_v  = (const float*)d_in[12];
    float* outp = (float*)d_out;

    const int B = in_sizes[0] / 784;      // 32768
    const int grid = B / SPB;             // 2048
    bnn_fused<<<grid, BLK, 0, stream>>>(xp, conv_w, conv_b,
                                        bn2_g, bn2_b, bn2_m, bn2_v,
                                        fc_w, fc_b, bn1_g, bn1_b, bn1_m, bn1_v,
                                        outp);
}